// Round 1
// baseline (406.138 us; speedup 1.0000x reference)
//
#include <hip/hip_runtime.h>
#include <hip/hip_bf16.h>
#include <math.h>

// DecoderActor: B=16384, N=20, DM=128.
// Algebraic reduction: with h = x@Wn^T + 1*(bn+lpg)^T, K=h@Wk^T+bk, Q=h@Wq^T+bq:
//   M*sqrt(dm) = x B x^T + x.a_vec (per row n) + x.b_vec (per row m) + c
// where B = Wn^T (Wk^T Wq) Wn is batch-independent, and a_vec,b_vec,c depend
// only on xg = max_n x[n,:] through Wg (precomputed fold matrices S1,S2,C2).
//
// ws layout (floats). Requires ws_size >= ~17.5 MB.
#define DM 128
#define NN 20
#define NB 16384

#define OFF_A      0
#define OFF_AT     16384
#define OFF_WA     32768
#define OFF_WAT    49152
#define OFF_AG     65536
#define OFF_BMAT   81920
#define OFF_S1T    98304
#define OFF_S2T    114688
#define OFF_C2T    131072
#define OFF_U0     147456
#define OFF_V0     147584
#define OFF_T0     147712
#define OFF_W1     147840
#define OFF_AT0    147968
#define OFF_A0     148096
#define OFF_B0     148224
#define OFF_C1     148352
#define OFF_C00    148480
#define OFF_CBASE  148481
#define OFF_AVEC   148992
#define OFF_BVEC   (148992 + 2097152)
#define OFF_CW     (148992 + 2*2097152)

#define INVS 0.08838834764831845f   // 1/sqrt(128)
#define LDSW 132                    // padded row stride (breaks bank conflicts)

// ---------- prep 1: A = Wk^T Wq (and A^T), u0, v0, t0, c00 ----------
__global__ void k_prep1(const float* __restrict__ Wk, const float* __restrict__ Wq,
                        const float* __restrict__ bk, const float* __restrict__ bq,
                        const float* __restrict__ bn, const float* __restrict__ bg,
                        float* __restrict__ ws) {
    const int bx = blockIdx.x, t = threadIdx.x;
    __shared__ float sbuf[128];
    if (bx < 128) {
        // A[e][f] = sum_d Wk[d][e] * Wq[d][f];  e = bx, f = t
        sbuf[t] = Wk[t * 128 + bx];          // colk[d]
        __syncthreads();
        float a = 0.f;
        #pragma unroll 8
        for (int d = 0; d < 128; ++d) a += sbuf[d] * Wq[d * 128 + t];
        ws[OFF_A  + bx * 128 + t] = a;
        ws[OFF_AT + t * 128 + bx] = a;
    } else {
        float u = 0.f, v = 0.f;
        #pragma unroll 8
        for (int d = 0; d < 128; ++d) {
            u += Wk[d * 128 + t] * bq[d];
            v += Wq[d * 128 + t] * bk[d];
        }
        ws[OFF_U0 + t] = u;
        ws[OFF_V0 + t] = v;
        ws[OFF_T0 + t] = bn[t] + bg[t];
        sbuf[t] = bk[t] * bq[t];
        __syncthreads();
        for (int s = 64; s > 0; s >>= 1) { if (t < s) sbuf[t] += sbuf[t + s]; __syncthreads(); }
        if (t == 0) ws[OFF_C00] = sbuf[0];
    }
}

// ---------- prep 2: WA = Wn^T A, WAT = Wn^T A^T, AG = A Wg; w1, At0, c_base ----------
__global__ void k_prep2(const float* __restrict__ Wn, const float* __restrict__ Wg,
                        float* __restrict__ ws) {
    const int bx = blockIdx.x, t = threadIdx.x;
    __shared__ float s1[128], s2[128];
    if (bx < 128) {
        const int r = bx;
        s1[t] = Wn[t * 128 + r];             // Wn[e][r]
        s2[t] = ws[OFF_A + r * 128 + t];     // A[r][e]
        __syncthreads();
        float wa = 0.f, wat = 0.f, ag = 0.f;
        #pragma unroll 4
        for (int e = 0; e < 128; ++e) {
            wa  += s1[e] * ws[OFF_A  + e * 128 + t];
            wat += s1[e] * ws[OFF_AT + e * 128 + t];
            ag  += s2[e] * Wg[e * 128 + t];
        }
        ws[OFF_WA  + r * 128 + t] = wa;      // WA[r][t]
        ws[OFF_WAT + r * 128 + t] = wat;     // WAT[r][t] = (W A^T)[r][t]
        ws[OFF_AG  + r * 128 + t] = ag;      // AG[r][t] = (A Wg)[r][t]
    } else {
        const float t0t = ws[OFF_T0 + t], u0t = ws[OFF_U0 + t], v0t = ws[OFF_V0 + t];
        float w1 = 0.f, at0 = 0.f;
        #pragma unroll 8
        for (int e = 0; e < 128; ++e) {
            const float t0e = ws[OFF_T0 + e];
            w1  += (ws[OFF_A + t * 128 + e] + ws[OFF_AT + t * 128 + e]) * t0e;
            at0 +=  ws[OFF_A + t * 128 + e] * t0e;
        }
        w1 += u0t + v0t;
        ws[OFF_W1  + t] = w1;
        ws[OFF_AT0 + t] = at0;
        s1[t] = t0t * (at0 + u0t + v0t);
        __syncthreads();
        for (int s = 64; s > 0; s >>= 1) { if (t < s) s1[t] += s1[t + s]; __syncthreads(); }
        if (t == 0) ws[OFF_CBASE] = s1[0] + ws[OFF_C00];
    }
}

// ---------- prep 3: Bmat, S1t, S2t, C2t; a0, b0, c1 ----------
__global__ void k_prep3(const float* __restrict__ Wn, const float* __restrict__ Wg,
                        float* __restrict__ ws) {
    const int bx = blockIdx.x, t = threadIdx.x;
    __shared__ float wa[128], wat[128], wgc[128];
    if (bx < 128) {
        const int r = bx;
        wa[t]  = ws[OFF_WA  + r * 128 + t];
        wat[t] = ws[OFF_WAT + r * 128 + t];
        wgc[t] = Wg[t * 128 + r];            // Wg[d][r]
        __syncthreads();
        float bm = 0.f, s1v = 0.f, s2v = 0.f, c2v = 0.f;
        #pragma unroll 4
        for (int f = 0; f < 128; ++f) {
            bm  += wa[f]  * Wn[f * 128 + t];             // B[r][t]
            s1v += wa[f]  * Wg[f * 128 + t];             // S1[r][t]
            s2v += wat[f] * Wg[f * 128 + t];             // S2[r][t]
            c2v += wgc[f] * ws[OFF_AG + f * 128 + t];    // C2[r][t]
        }
        ws[OFF_BMAT + r * 128 + t] = bm;
        ws[OFF_S1T + t * 128 + r] = s1v;     // S1t[m][j] = S1[j][m]
        ws[OFF_S2T + t * 128 + r] = s2v;
        ws[OFF_C2T + t * 128 + r] = c2v;
    } else {
        float a0 = 0.f, b0 = 0.f, c1 = 0.f;
        #pragma unroll 8
        for (int f = 0; f < 128; ++f) {
            a0 += ws[OFF_WA  + t * 128 + f] * ws[OFF_T0 + f] + Wn[f * 128 + t] * ws[OFF_U0 + f];
            b0 += ws[OFF_WAT + t * 128 + f] * ws[OFF_T0 + f] + Wn[f * 128 + t] * ws[OFF_V0 + f];
            c1 += Wg[f * 128 + t] * ws[OFF_W1 + f];
        }
        ws[OFF_A0 + t] = a0;
        ws[OFF_B0 + t] = b0;
        ws[OFF_C1 + t] = c1;
    }
}

// ---------- per-batch a_vec, b_vec, c from xg (16 batches / block) ----------
__global__ __launch_bounds__(256) void k_abc(const float* __restrict__ x, float* __restrict__ ws) {
    const int t = threadIdx.x;
    const int b0 = blockIdx.x * 16;
    __shared__ float xg[16][LDSW];
    __shared__ float part[4][8];

    {   // phase A: xg = max over nodes, vectorized float4
        const int j4 = t & 31, s = t >> 5;
        for (int bi = s; bi < 16; bi += 8) {
            const float4* xp = (const float4*)(x + (size_t)(b0 + bi) * (NN * DM));
            float4 m = xp[j4];
            #pragma unroll
            for (int n = 1; n < NN; ++n) {
                float4 v = xp[n * 32 + j4];
                m.x = fmaxf(m.x, v.x); m.y = fmaxf(m.y, v.y);
                m.z = fmaxf(m.z, v.z); m.w = fmaxf(m.w, v.w);
            }
            xg[bi][j4 * 4 + 0] = m.x; xg[bi][j4 * 4 + 1] = m.y;
            xg[bi][j4 * 4 + 2] = m.z; xg[bi][j4 * 4 + 3] = m.w;
        }
    }
    __syncthreads();

    const int j = t & 127, h = t >> 7;
    float acc[8];

#define MATVEC16(MOFF)                                                     \
    {                                                                      \
        _Pragma("unroll")                                                  \
        for (int k = 0; k < 8; ++k) acc[k] = 0.f;                          \
        for (int m = 0; m < 128; m += 4) {                                 \
            const float s0 = ws[(MOFF) + (m + 0) * 128 + j];               \
            const float s1v = ws[(MOFF) + (m + 1) * 128 + j];              \
            const float s2v = ws[(MOFF) + (m + 2) * 128 + j];              \
            const float s3v = ws[(MOFF) + (m + 3) * 128 + j];              \
            _Pragma("unroll")                                              \
            for (int k = 0; k < 8; ++k) {                                  \
                const int bi = h + 2 * k;                                  \
                acc[k] += xg[bi][m] * s0 + xg[bi][m + 1] * s1v             \
                        + xg[bi][m + 2] * s2v + xg[bi][m + 3] * s3v;       \
            }                                                              \
        }                                                                  \
    }

    MATVEC16(OFF_S1T);
    {
        const float a0j = ws[OFF_A0 + j];
        #pragma unroll
        for (int k = 0; k < 8; ++k)
            ws[OFF_AVEC + (size_t)(b0 + h + 2 * k) * 128 + j] = a0j + acc[k];
    }
    MATVEC16(OFF_S2T);
    {
        const float b0j = ws[OFF_B0 + j];
        #pragma unroll
        for (int k = 0; k < 8; ++k)
            ws[OFF_BVEC + (size_t)(b0 + h + 2 * k) * 128 + j] = b0j + acc[k];
    }
    MATVEC16(OFF_C2T);
    {
        const float c1j = ws[OFF_C1 + j];
        const int lane = t & 63, wid = t >> 6;
        #pragma unroll
        for (int k = 0; k < 8; ++k) {
            float val = xg[h + 2 * k][j] * (acc[k] + c1j);
            for (int off = 32; off > 0; off >>= 1) val += __shfl_down(val, off);
            if (lane == 0) part[wid][k] = val;
        }
        __syncthreads();
        if (t < 16) {
            const int bi = t, hh = bi & 1, kk = bi >> 1;
            ws[OFF_CW + b0 + bi] = ws[OFF_CBASE] + part[2 * hh][kk] + part[2 * hh + 1][kk];
        }
    }
#undef MATVEC16
}

// ---------- main: F = x*B, M = F x^T, tanh-clip, flattened softmax ----------
__global__ __launch_bounds__(256) void k_main(const float* __restrict__ x,
                                              const float* __restrict__ ws,
                                              float* __restrict__ out) {
    const int t = threadIdx.x;
    const int b = blockIdx.x;
    __shared__ float xs[NN * LDSW];
    __shared__ float fs[NN * LDSW];
    __shared__ float avec[128], bvec[128];
    __shared__ float ab[40];        // alpha[0..19], beta[20..39]
    __shared__ float abp[40][4];
    __shared__ float zb[400];
    __shared__ float red[256];
    __shared__ float csc;

    {   // stage x[b] into LDS (padded rows)
        const float4* xp = (const float4*)(x + (size_t)b * (NN * DM));
        for (int i = t; i < NN * 32; i += 256) {
            float4 v = xp[i];
            float* dst = xs + (i >> 5) * LDSW + (i & 31) * 4;
            dst[0] = v.x; dst[1] = v.y; dst[2] = v.z; dst[3] = v.w;
        }
        if (t < 128) avec[t] = ws[OFF_AVEC + (size_t)b * 128 + t];
        else         bvec[t - 128] = ws[OFF_BVEC + (size_t)b * 128 + (t - 128)];
        if (t == 0) csc = ws[OFF_CW + b];
    }
    __syncthreads();

    // alpha[n] = x[n].avec, beta[m] = x[m].bvec (4 partial lanes each)
    if (t < 160) {
        const int q = t & 3, idx = t >> 2;      // idx in [0,40)
        const int n = idx % 20;
        const float* vec = (idx < 20) ? avec : bvec;
        const float* xr = xs + n * LDSW + q * 32;
        float s = 0.f;
        #pragma unroll
        for (int e = 0; e < 32; ++e) s += xr[e] * vec[q * 32 + e];
        abp[idx][q] = s;
    }
    __syncthreads();
    if (t < 40) ab[t] = abp[t][0] + abp[t][1] + abp[t][2] + abp[t][3];

    // F phase: F[n][j] = sum_e xs[n][e] * B[e][j]
    {
        const int j = t & 127, h = t >> 7;
        float f[10];
        #pragma unroll
        for (int i = 0; i < 10; ++i) f[i] = 0.f;
        const float* Bp = ws + OFF_BMAT;
        for (int e = 0; e < 128; e += 4) {
            const float b0v = Bp[(e + 0) * 128 + j];
            const float b1v = Bp[(e + 1) * 128 + j];
            const float b2v = Bp[(e + 2) * 128 + j];
            const float b3v = Bp[(e + 3) * 128 + j];
            #pragma unroll
            for (int i = 0; i < 10; ++i) {
                const float* xr = xs + (h + 2 * i) * LDSW + e;
                f[i] += xr[0] * b0v + xr[1] * b1v + xr[2] * b2v + xr[3] * b3v;
            }
        }
        #pragma unroll
        for (int i = 0; i < 10; ++i) fs[(h + 2 * i) * LDSW + j] = f[i];
    }
    __syncthreads();

    // M phase + tanh clip
    float lmax = -INFINITY;
    for (int idx = t; idx < 400; idx += 256) {
        const int n = idx / 20, m = idx % 20;
        const float* fr = fs + n * LDSW;
        const float* xr = xs + m * LDSW;
        float s = 0.f;
        #pragma unroll 8
        for (int jj = 0; jj < 128; ++jj) s += fr[jj] * xr[jj];
        const float Ms = (s + ab[n] + ab[20 + m] + csc) * INVS;
        float z = 10.f * tanhf(Ms);
        if (n == m) z = -1e30f;
        zb[idx] = z;
        lmax = fmaxf(lmax, z);
    }

    // flattened softmax over 400
    red[t] = lmax; __syncthreads();
    for (int s = 128; s > 0; s >>= 1) { if (t < s) red[t] = fmaxf(red[t], red[t + s]); __syncthreads(); }
    const float gmax = red[0];
    __syncthreads();
    float lsum = 0.f;
    for (int idx = t; idx < 400; idx += 256) {
        const float le = __expf(zb[idx] - gmax);
        zb[idx] = le;
        lsum += le;
    }
    red[t] = lsum; __syncthreads();
    for (int s = 128; s > 0; s >>= 1) { if (t < s) red[t] += red[t + s]; __syncthreads(); }
    const float inv = 1.f / red[0];
    for (int idx = t; idx < 400; idx += 256)
        out[(size_t)b * 400 + idx] = zb[idx] * inv;
}

extern "C" void kernel_launch(void* const* d_in, const int* in_sizes, int n_in,
                              void* d_out, int out_size, void* d_ws, size_t ws_size,
                              hipStream_t stream) {
    const float* x  = (const float*)d_in[0];
    const float* Wg = (const float*)d_in[1];
    const float* bg = (const float*)d_in[2];
    const float* Wn = (const float*)d_in[3];
    const float* bn = (const float*)d_in[4];
    const float* Wk = (const float*)d_in[5];
    const float* bk = (const float*)d_in[6];
    const float* Wq = (const float*)d_in[7];
    const float* bq = (const float*)d_in[8];
    float* out = (float*)d_out;
    float* ws  = (float*)d_ws;

    k_prep1<<<129, 128, 0, stream>>>(Wk, Wq, bk, bq, bn, bg, ws);
    k_prep2<<<129, 128, 0, stream>>>(Wn, Wg, ws);
    k_prep3<<<129, 128, 0, stream>>>(Wn, Wg, ws);
    k_abc<<<1024, 256, 0, stream>>>(x, ws);
    k_main<<<NB, 256, 0, stream>>>(x, ws, out);
}

// Round 2
// 140.502 us; speedup vs baseline: 2.8906x; 2.8906x over previous
//
#include <hip/hip_runtime.h>
#include <hip/hip_bf16.h>
#include <math.h>

// DecoderActor: B=16384, N=20, DM=128.
// M*sqrt(dm) = x B x^T + alpha_n + beta_m + c, with B = Wn^T(Wk^T Wq)Wn and
// alpha/beta/c derived from xg = max_n x[n,:]. Round 2: fused single kernel,
// all matmul phases on mfma_f32_16x16x32_f16 (fp16 in, fp32 acc).
#define DM 128
#define NN 20
#define NB 16384
#define BPB 8

#define OFF_A      0
#define OFF_AT     16384
#define OFF_WA     32768
#define OFF_WAT    49152
#define OFF_AG     65536
#define OFF_BMAT   81920
#define OFF_S1T    98304
#define OFF_S2T    114688
#define OFF_C2T    131072
#define OFF_U0     147456
#define OFF_V0     147584
#define OFF_T0     147712
#define OFF_W1     147840
#define OFF_AT0    147968
#define OFF_A0     148096
#define OFF_B0     148224
#define OFF_C1     148352
#define OFF_C00    148480
#define OFF_CBASE  148481
// fp16 fragment arrays (packed by k_prep4): fragB = 16384 halfs, fragS = 49152 halfs
#define OFF_FRAGB  149504
#define OFF_FRAGS  (149504 + 8192)

#define INVS 0.08838834764831845f   // 1/sqrt(128)

typedef _Float16 h16;
typedef h16 half8 __attribute__((ext_vector_type(8)));
typedef h16 half4v __attribute__((ext_vector_type(4)));
typedef float f32x4 __attribute__((ext_vector_type(4)));

// XOR swizzle in h16 units: spreads 256B-strided rows across LDS banks.
__device__ __forceinline__ int swz(int row, int col) {
    return (row * 128 + col) ^ ((row & 7) << 3);
}

// ---------- prep 1: A = Wk^T Wq (and A^T), u0, v0, t0, c00 ----------
__global__ void k_prep1(const float* __restrict__ Wk, const float* __restrict__ Wq,
                        const float* __restrict__ bk, const float* __restrict__ bq,
                        const float* __restrict__ bn, const float* __restrict__ bg,
                        float* __restrict__ ws) {
    const int bx = blockIdx.x, t = threadIdx.x;
    __shared__ float sbuf[128];
    if (bx < 128) {
        sbuf[t] = Wk[t * 128 + bx];
        __syncthreads();
        float a = 0.f;
        #pragma unroll 8
        for (int d = 0; d < 128; ++d) a += sbuf[d] * Wq[d * 128 + t];
        ws[OFF_A  + bx * 128 + t] = a;
        ws[OFF_AT + t * 128 + bx] = a;
    } else {
        float u = 0.f, v = 0.f;
        #pragma unroll 8
        for (int d = 0; d < 128; ++d) {
            u += Wk[d * 128 + t] * bq[d];
            v += Wq[d * 128 + t] * bk[d];
        }
        ws[OFF_U0 + t] = u;
        ws[OFF_V0 + t] = v;
        ws[OFF_T0 + t] = bn[t] + bg[t];
        sbuf[t] = bk[t] * bq[t];
        __syncthreads();
        for (int s = 64; s > 0; s >>= 1) { if (t < s) sbuf[t] += sbuf[t + s]; __syncthreads(); }
        if (t == 0) ws[OFF_C00] = sbuf[0];
    }
}

// ---------- prep 2: WA = Wn^T A, WAT = Wn^T A^T, AG = A Wg; w1, At0, c_base ----------
__global__ void k_prep2(const float* __restrict__ Wn, const float* __restrict__ Wg,
                        float* __restrict__ ws) {
    const int bx = blockIdx.x, t = threadIdx.x;
    __shared__ float s1[128], s2[128];
    if (bx < 128) {
        const int r = bx;
        s1[t] = Wn[t * 128 + r];
        s2[t] = ws[OFF_A + r * 128 + t];
        __syncthreads();
        float wa = 0.f, wat = 0.f, ag = 0.f;
        #pragma unroll 4
        for (int e = 0; e < 128; ++e) {
            wa  += s1[e] * ws[OFF_A  + e * 128 + t];
            wat += s1[e] * ws[OFF_AT + e * 128 + t];
            ag  += s2[e] * Wg[e * 128 + t];
        }
        ws[OFF_WA  + r * 128 + t] = wa;
        ws[OFF_WAT + r * 128 + t] = wat;
        ws[OFF_AG  + r * 128 + t] = ag;
    } else {
        const float t0t = ws[OFF_T0 + t], u0t = ws[OFF_U0 + t], v0t = ws[OFF_V0 + t];
        float w1 = 0.f, at0 = 0.f;
        #pragma unroll 8
        for (int e = 0; e < 128; ++e) {
            const float t0e = ws[OFF_T0 + e];
            w1  += (ws[OFF_A + t * 128 + e] + ws[OFF_AT + t * 128 + e]) * t0e;
            at0 +=  ws[OFF_A + t * 128 + e] * t0e;
        }
        w1 += u0t + v0t;
        ws[OFF_W1  + t] = w1;
        ws[OFF_AT0 + t] = at0;
        s1[t] = t0t * (at0 + u0t + v0t);
        __syncthreads();
        for (int s = 64; s > 0; s >>= 1) { if (t < s) s1[t] += s1[t + s]; __syncthreads(); }
        if (t == 0) ws[OFF_CBASE] = s1[0] + ws[OFF_C00];
    }
}

// ---------- prep 3: Bmat, S1t, S2t, C2t; a0, b0, c1 ----------
__global__ void k_prep3(const float* __restrict__ Wn, const float* __restrict__ Wg,
                        float* __restrict__ ws) {
    const int bx = blockIdx.x, t = threadIdx.x;
    __shared__ float wa[128], wat[128], wgc[128];
    if (bx < 128) {
        const int r = bx;
        wa[t]  = ws[OFF_WA  + r * 128 + t];
        wat[t] = ws[OFF_WAT + r * 128 + t];
        wgc[t] = Wg[t * 128 + r];
        __syncthreads();
        float bm = 0.f, s1v = 0.f, s2v = 0.f, c2v = 0.f;
        #pragma unroll 4
        for (int f = 0; f < 128; ++f) {
            bm  += wa[f]  * Wn[f * 128 + t];
            s1v += wa[f]  * Wg[f * 128 + t];
            s2v += wat[f] * Wg[f * 128 + t];
            c2v += wgc[f] * ws[OFF_AG + f * 128 + t];
        }
        ws[OFF_BMAT + r * 128 + t] = bm;
        ws[OFF_S1T + t * 128 + r] = s1v;
        ws[OFF_S2T + t * 128 + r] = s2v;
        ws[OFF_C2T + t * 128 + r] = c2v;
    } else {
        float a0 = 0.f, b0 = 0.f, c1 = 0.f;
        #pragma unroll 8
        for (int f = 0; f < 128; ++f) {
            a0 += ws[OFF_WA  + t * 128 + f] * ws[OFF_T0 + f] + Wn[f * 128 + t] * ws[OFF_U0 + f];
            b0 += ws[OFF_WAT + t * 128 + f] * ws[OFF_T0 + f] + Wn[f * 128 + t] * ws[OFF_V0 + f];
            c1 += Wg[f * 128 + t] * ws[OFF_W1 + f];
        }
        ws[OFF_A0 + t] = a0;
        ws[OFF_B0 + t] = b0;
        ws[OFF_C1 + t] = c1;
    }
}

// ---------- prep 4: pack fp16 MFMA fragments with f(g,e) = 8g+e ----------
// fragB[ct<8][ks<4][lane][e] = Bmat[32ks+8(l>>4)+e][16ct+(l&15)]
// fragS[ct<24][ks<4][lane][e] = Scat[32ks+8(l>>4)+e][16ct+(l&15)],
//   Scat[k][j] = S1T[k][j] (j<128) | S2T[k][j-128] | C2T[k][j-256]
__global__ void k_prep4(float* __restrict__ ws) {
    h16* fB = (h16*)(ws + OFF_FRAGB);
    h16* fS = (h16*)(ws + OFF_FRAGS);
    const int idx = blockIdx.x * 256 + threadIdx.x;     // grid covers 65536
    if (idx < 16384) {
        const int e = idx & 7, l = (idx >> 3) & 63, ks = (idx >> 9) & 3, ct = idx >> 11;
        const int k = 32 * ks + 8 * (l >> 4) + e, j = 16 * ct + (l & 15);
        fB[idx] = (h16)ws[OFF_BMAT + k * 128 + j];
    } else {
        const int sidx = idx - 16384;
        const int e = sidx & 7, l = (sidx >> 3) & 63, ks = (sidx >> 9) & 3, ct = sidx >> 11;
        const int k = 32 * ks + 8 * (l >> 4) + e, j = 16 * ct + (l & 15);
        float v;
        if (j < 128)      v = ws[OFF_S1T + k * 128 + j];
        else if (j < 256) v = ws[OFF_S2T + k * 128 + (j - 128)];
        else              v = ws[OFF_C2T + k * 128 + (j - 256)];
        fS[sidx] = (h16)v;
    }
}

// ---------- fused main ----------
__global__ __launch_bounds__(256) void k_fused(const float* __restrict__ x,
                                               const float* __restrict__ ws,
                                               float* __restrict__ out) {
    __shared__ __align__(16) h16 xh[BPB * 20 * 128];   // 40960 B, swizzled
    __shared__ __align__(16) h16 xgl[BPB * 128];       // 2048 B, swizzled
    __shared__ __align__(16) h16 fFs[32 * 128];        // 8192 B, swizzled
    __shared__ float avbc[BPB][384];                   // 12288 B
    __shared__ float ab[BPB][40];                      // 1280 B
    __shared__ float cbs[BPB];
    __shared__ float red[8];

    const int t = threadIdx.x;
    const int lane = t & 63;
    const int w = t >> 6;
    const int lc = lane & 15;
    const int lg = lane >> 4;
    const int b0 = blockIdx.x * BPB;
    const half8 h8z = {0, 0, 0, 0, 0, 0, 0, 0};

    // ---- prologue: load x -> fp16 LDS (swizzled) + xg (col-max) ----
    {
        const int lb = t >> 5, j4 = t & 31;
        const float4* xp = (const float4*)(x + (size_t)(b0 + lb) * (NN * DM));
        float4 mx = xp[j4];
        {
            half4v hv = { (h16)mx.x, (h16)mx.y, (h16)mx.z, (h16)mx.w };
            *(half4v*)(xh + lb * 2560 + swz(0, 4 * j4)) = hv;
        }
        #pragma unroll
        for (int n = 1; n < NN; ++n) {
            float4 v = xp[n * 32 + j4];
            half4v hv = { (h16)v.x, (h16)v.y, (h16)v.z, (h16)v.w };
            *(half4v*)(xh + lb * 2560 + swz(n, 4 * j4)) = hv;
            mx.x = fmaxf(mx.x, v.x); mx.y = fmaxf(mx.y, v.y);
            mx.z = fmaxf(mx.z, v.z); mx.w = fmaxf(mx.w, v.w);
        }
        half4v hg = { (h16)mx.x, (h16)mx.y, (h16)mx.z, (h16)mx.w };
        *(half4v*)(xgl + swz(lb, 4 * j4)) = hg;
    }
    __syncthreads();

    // ---- matvec: AV = XG * Scat via MFMA (rows = batches, 8 valid of 16) ----
    {
        const half8* fS = (const half8*)(ws + OFF_FRAGS);
        f32x4 sacc[6];
        #pragma unroll
        for (int i = 0; i < 6; ++i) sacc[i] = (f32x4){0.f, 0.f, 0.f, 0.f};
        #pragma unroll
        for (int ks = 0; ks < 4; ++ks) {
            half8 a = *(const half8*)(xgl + swz(lc < BPB ? lc : 0, 32 * ks + 8 * lg));
            if (lc >= BPB) a = h8z;
            #pragma unroll
            for (int i = 0; i < 6; ++i) {
                const int ct = 6 * w + i;
                half8 bfr = fS[(ct * 4 + ks) * 64 + lane];
                sacc[i] = __builtin_amdgcn_mfma_f32_16x16x32_f16(a, bfr, sacc[i], 0, 0, 0);
            }
        }
        #pragma unroll
        for (int i = 0; i < 6; ++i) {
            const int ct = 6 * w + i;
            #pragma unroll
            for (int r = 0; r < 4; ++r) {
                const int bi = lg * 4 + r;
                if (bi < BPB) avbc[bi][16 * ct + lc] = sacc[i][r];
            }
        }
    }
    __syncthreads();

    // ---- bias pass: avbc += [a0 | b0 | c1] ----
    {
        const float* a0p = ws + OFF_A0;
        const float* b0p = ws + OFF_B0;
        const float* c1p = ws + OFF_C1;
        for (int k = t; k < BPB * 384; k += 256) {
            const int bb = k / 384, col = k % 384;
            const float add = (col < 128) ? a0p[col]
                            : (col < 256) ? b0p[col - 128] : c1p[col - 256];
            avbc[bb][col] += add;
        }
    }
    __syncthreads();

    // ---- alpha/beta dots: ab[b][n] = x[n].avec, ab[b][20+m] = x[m].bvec ----
    for (int d = t; d < BPB * 40; d += 256) {
        const int bb = d / 40, i = d % 40;
        const int row = (i < 20) ? i : (i - 20);
        const float* av = avbc[bb] + ((i < 20) ? 0 : 128);
        float s = 0.f;
        #pragma unroll
        for (int c8 = 0; c8 < 16; ++c8) {
            half8 xv = *(const half8*)(xh + bb * 2560 + swz(row, 8 * c8));
            #pragma unroll
            for (int e = 0; e < 8; ++e) s += (float)xv[e] * av[8 * c8 + e];
        }
        ab[bb][i] = s;
    }
    // ---- c scalar: cbs[b] = cbase + sum_j xg[j]*(cvec[j]+c1[j]) ----
    {
        const int bb = t >> 5, j0 = (t & 31) * 4;
        float s = 0.f;
        #pragma unroll
        for (int q = 0; q < 4; ++q) {
            const int col = j0 + q;
            s += (float)xgl[swz(bb, col)] * avbc[bb][256 + col];
        }
        #pragma unroll
        for (int off = 16; off > 0; off >>= 1) s += __shfl_down(s, off, 32);
        if ((t & 31) == 0) cbs[bb] = s + ws[OFF_CBASE];
    }
    __syncthreads();

    // ---- load B fragments into registers (held across batch loop) ----
    half8 bB[2][4];
    {
        const half8* fB = (const half8*)(ws + OFF_FRAGB);
        #pragma unroll
        for (int ctl = 0; ctl < 2; ++ctl)
            #pragma unroll
            for (int ks = 0; ks < 4; ++ks)
                bB[ctl][ks] = fB[((2 * w + ctl) * 4 + ks) * 64 + lane];
    }

    const int rtM = w >> 1, ctM = w & 1;
    const int mcol = 16 * ctM + lc;

    for (int b = 0; b < BPB; ++b) {
        const h16* xb = xh + b * 2560;
        // -- F phase: F = x * B  (rows 20..31 zero via masked A) --
        f32x4 facc[2][2];
        #pragma unroll
        for (int rt = 0; rt < 2; ++rt)
            #pragma unroll
            for (int ctl = 0; ctl < 2; ++ctl) facc[rt][ctl] = (f32x4){0.f, 0.f, 0.f, 0.f};
        #pragma unroll
        for (int ks = 0; ks < 4; ++ks) {
            half8 a0f = *(const half8*)(xb + swz(lc, 32 * ks + 8 * lg));
            const int r1 = 16 + lc;
            half8 a1f = *(const half8*)(xb + swz(r1 < NN ? r1 : 0, 32 * ks + 8 * lg));
            if (r1 >= NN) a1f = h8z;
            #pragma unroll
            for (int ctl = 0; ctl < 2; ++ctl) {
                facc[0][ctl] = __builtin_amdgcn_mfma_f32_16x16x32_f16(a0f, bB[ctl][ks], facc[0][ctl], 0, 0, 0);
                facc[1][ctl] = __builtin_amdgcn_mfma_f32_16x16x32_f16(a1f, bB[ctl][ks], facc[1][ctl], 0, 0, 0);
            }
        }
        // -- stage F as fp16 into LDS --
        #pragma unroll
        for (int rt = 0; rt < 2; ++rt)
            #pragma unroll
            for (int ctl = 0; ctl < 2; ++ctl)
                #pragma unroll
                for (int r = 0; r < 4; ++r)
                    fFs[swz(16 * rt + lg * 4 + r, 16 * (2 * w + ctl) + lc)] = (h16)facc[rt][ctl][r];
        __syncthreads();
        // -- M phase: wave w owns quadrant (rtM, ctM), full K=128 --
        f32x4 macc = {0.f, 0.f, 0.f, 0.f};
        #pragma unroll
        for (int ks = 0; ks < 4; ++ks) {
            half8 aF = *(const half8*)(fFs + swz(16 * rtM + lc, 32 * ks + 8 * lg));
            half8 bX = *(const half8*)(xb + swz(mcol < NN ? mcol : 0, 32 * ks + 8 * lg));
            if (mcol >= NN) bX = h8z;
            macc = __builtin_amdgcn_mfma_f32_16x16x32_f16(aF, bX, macc, 0, 0, 0);
        }
        // -- epilogue: tanh clip + flattened softmax over 400 --
        float z[4], lm = -INFINITY;
        #pragma unroll
        for (int r = 0; r < 4; ++r) {
            const int n = 16 * rtM + lg * 4 + r;
            const bool valid = (n < NN) && (mcol < NN);
            const float Mv = (macc[r] + ab[b][n] + ab[b][20 + mcol] + cbs[b]) * INVS;
            float zz = 10.f - 20.f / (__expf(2.f * Mv) + 1.f);   // 10*tanh(Mv)
            if (n == mcol) zz = -1e30f;
            z[r] = zz;
            if (valid) lm = fmaxf(lm, zz);
        }
        #pragma unroll
        for (int off = 32; off > 0; off >>= 1) lm = fmaxf(lm, __shfl_xor(lm, off));
        if (lane == 0) red[w] = lm;
        __syncthreads();
        const float gmax = fmaxf(fmaxf(red[0], red[1]), fmaxf(red[2], red[3]));
        float ez[4], ls = 0.f;
        #pragma unroll
        for (int r = 0; r < 4; ++r) {
            const int n = 16 * rtM + lg * 4 + r;
            const bool valid = (n < NN) && (mcol < NN);
            const float e = valid ? __expf(z[r] - gmax) : 0.f;
            ez[r] = e; ls += e;
        }
        #pragma unroll
        for (int off = 32; off > 0; off >>= 1) ls += __shfl_xor(ls, off);
        if (lane == 0) red[4 + w] = ls;
        __syncthreads();
        const float invS = 1.f / (red[4] + red[5] + red[6] + red[7]);
        float* ob = out + (size_t)(b0 + b) * 400;
        #pragma unroll
        for (int r = 0; r < 4; ++r) {
            const int n = 16 * rtM + lg * 4 + r;
            if (n < NN && mcol < NN) ob[n * 20 + mcol] = ez[r] * invS;
        }
    }
}

extern "C" void kernel_launch(void* const* d_in, const int* in_sizes, int n_in,
                              void* d_out, int out_size, void* d_ws, size_t ws_size,
                              hipStream_t stream) {
    const float* x  = (const float*)d_in[0];
    const float* Wg = (const float*)d_in[1];
    const float* bg = (const float*)d_in[2];
    const float* Wn = (const float*)d_in[3];
    const float* bn = (const float*)d_in[4];
    const float* Wk = (const float*)d_in[5];
    const float* bk = (const float*)d_in[6];
    const float* Wq = (const float*)d_in[7];
    const float* bq = (const float*)d_in[8];
    float* out = (float*)d_out;
    float* ws  = (float*)d_ws;

    k_prep1<<<129, 128, 0, stream>>>(Wk, Wq, bk, bq, bn, bg, ws);
    k_prep2<<<129, 128, 0, stream>>>(Wn, Wg, ws);
    k_prep3<<<129, 128, 0, stream>>>(Wn, Wg, ws);
    k_prep4<<<256, 256, 0, stream>>>(ws);
    k_fused<<<NB / BPB, 256, 0, stream>>>(x, ws, out);
}

// Round 5
// 126.345 us; speedup vs baseline: 3.2145x; 1.1121x over previous
//
#include <hip/hip_runtime.h>
#include <hip/hip_bf16.h>
#include <math.h>

// DecoderActor: B=16384, N=20, DM=128.
// M*sqrt(dm) = x B x^T + alpha_n + beta_m + c, B = Wn^T(Wk^T Wq)Wn,
// alpha/beta/c derived from xg = max_n x[n,:].
// Round 5: retreat to the HW-verified 16x16x32 fragment scheme (round 2
// passed), restructured as one-wave-per-batch with zero barriers after the
// prologue. No 32x32 MFMA, no inline-asm cross-lane, no new layout math.
#define DM 128
#define NN 20
#define NB 16384
#define BPB 4

#define OFF_A      0
#define OFF_AT     16384
#define OFF_WA     32768
#define OFF_WAT    49152
#define OFF_AG     65536
#define OFF_BMAT   81920
#define OFF_S1T    98304
#define OFF_S2T    114688
#define OFF_C2T    131072
#define OFF_U0     147456
#define OFF_V0     147584
#define OFF_T0     147712
#define OFF_W1     147840
#define OFF_AT0    147968
#define OFF_A0     148096
#define OFF_B0     148224
#define OFF_C1     148352
#define OFF_C00    148480
#define OFF_CBASE  148481
// fp16 fragment arrays (packed by k_prep4, round-2 layout)
#define OFF_FRAGB  149504            // 16384 h16 : Bmat frags (16x16x32 B-op, 8 ct)
#define OFF_FRAGS  (149504 + 8192)   // 49152 h16 : matvec S frags (16x16x32 B-op, 24 ct)

#define INVS 0.08838834764831845f    // 1/sqrt(128)
#define FW 132                       // fFs row stride in h16 (bank spread, no XOR)

typedef _Float16 h16;
typedef h16 half8 __attribute__((ext_vector_type(8)));
typedef h16 half4v __attribute__((ext_vector_type(4)));
typedef float f32x4 __attribute__((ext_vector_type(4)));

#define MFMA16(a, b, c) __builtin_amdgcn_mfma_f32_16x16x32_f16((a), (b), (c), 0, 0, 0)

// round-2 verified XOR swizzle for xh/xgl (h16 units)
__device__ __forceinline__ int swz(int row, int col) {
    return (row * 128 + col) ^ ((row & 7) << 3);
}

// ---------- prep 1: A = Wk^T Wq (and A^T), u0, v0, t0, c00 ----------
__global__ void k_prep1(const float* __restrict__ Wk, const float* __restrict__ Wq,
                        const float* __restrict__ bk, const float* __restrict__ bq,
                        const float* __restrict__ bn, const float* __restrict__ bg,
                        float* __restrict__ ws) {
    const int bx = blockIdx.x, t = threadIdx.x;
    __shared__ float sbuf[128];
    if (bx < 128) {
        sbuf[t] = Wk[t * 128 + bx];
        __syncthreads();
        float a = 0.f;
        #pragma unroll 8
        for (int d = 0; d < 128; ++d) a += sbuf[d] * Wq[d * 128 + t];
        ws[OFF_A  + bx * 128 + t] = a;
        ws[OFF_AT + t * 128 + bx] = a;
    } else {
        float u = 0.f, v = 0.f;
        #pragma unroll 8
        for (int d = 0; d < 128; ++d) {
            u += Wk[d * 128 + t] * bq[d];
            v += Wq[d * 128 + t] * bk[d];
        }
        ws[OFF_U0 + t] = u;
        ws[OFF_V0 + t] = v;
        ws[OFF_T0 + t] = bn[t] + bg[t];
        sbuf[t] = bk[t] * bq[t];
        __syncthreads();
        for (int s = 64; s > 0; s >>= 1) { if (t < s) sbuf[t] += sbuf[t + s]; __syncthreads(); }
        if (t == 0) ws[OFF_C00] = sbuf[0];
    }
}

// ---------- prep 2: WA = Wn^T A, WAT = Wn^T A^T, AG = A Wg; w1, At0, c_base ----------
__global__ void k_prep2(const float* __restrict__ Wn, const float* __restrict__ Wg,
                        float* __restrict__ ws) {
    const int bx = blockIdx.x, t = threadIdx.x;
    __shared__ float s1[128], s2[128];
    if (bx < 128) {
        const int r = bx;
        s1[t] = Wn[t * 128 + r];
        s2[t] = ws[OFF_A + r * 128 + t];
        __syncthreads();
        float wa = 0.f, wat = 0.f, ag = 0.f;
        #pragma unroll 4
        for (int e = 0; e < 128; ++e) {
            wa  += s1[e] * ws[OFF_A  + e * 128 + t];
            wat += s1[e] * ws[OFF_AT + e * 128 + t];
            ag  += s2[e] * Wg[e * 128 + t];
        }
        ws[OFF_WA  + r * 128 + t] = wa;
        ws[OFF_WAT + r * 128 + t] = wat;
        ws[OFF_AG  + r * 128 + t] = ag;
    } else {
        const float t0t = ws[OFF_T0 + t], u0t = ws[OFF_U0 + t], v0t = ws[OFF_V0 + t];
        float w1 = 0.f, at0 = 0.f;
        #pragma unroll 8
        for (int e = 0; e < 128; ++e) {
            const float t0e = ws[OFF_T0 + e];
            w1  += (ws[OFF_A + t * 128 + e] + ws[OFF_AT + t * 128 + e]) * t0e;
            at0 +=  ws[OFF_A + t * 128 + e] * t0e;
        }
        w1 += u0t + v0t;
        ws[OFF_W1  + t] = w1;
        ws[OFF_AT0 + t] = at0;
        s1[t] = t0t * (at0 + u0t + v0t);
        __syncthreads();
        for (int s = 64; s > 0; s >>= 1) { if (t < s) s1[t] += s1[t + s]; __syncthreads(); }
        if (t == 0) ws[OFF_CBASE] = s1[0] + ws[OFF_C00];
    }
}

// ---------- prep 3: Bmat, S1t, S2t, C2t; a0, b0, c1 ----------
__global__ void k_prep3(const float* __restrict__ Wn, const float* __restrict__ Wg,
                        float* __restrict__ ws) {
    const int bx = blockIdx.x, t = threadIdx.x;
    __shared__ float wa[128], wat[128], wgc[128];
    if (bx < 128) {
        const int r = bx;
        wa[t]  = ws[OFF_WA  + r * 128 + t];
        wat[t] = ws[OFF_WAT + r * 128 + t];
        wgc[t] = Wg[t * 128 + r];
        __syncthreads();
        float bm = 0.f, s1v = 0.f, s2v = 0.f, c2v = 0.f;
        #pragma unroll 4
        for (int f = 0; f < 128; ++f) {
            bm  += wa[f]  * Wn[f * 128 + t];
            s1v += wa[f]  * Wg[f * 128 + t];
            s2v += wat[f] * Wg[f * 128 + t];
            c2v += wgc[f] * ws[OFF_AG + f * 128 + t];
        }
        ws[OFF_BMAT + r * 128 + t] = bm;
        ws[OFF_S1T + t * 128 + r] = s1v;
        ws[OFF_S2T + t * 128 + r] = s2v;
        ws[OFF_C2T + t * 128 + r] = c2v;
    } else {
        float a0 = 0.f, b0 = 0.f, c1 = 0.f;
        #pragma unroll 8
        for (int f = 0; f < 128; ++f) {
            a0 += ws[OFF_WA  + t * 128 + f] * ws[OFF_T0 + f] + Wn[f * 128 + t] * ws[OFF_U0 + f];
            b0 += ws[OFF_WAT + t * 128 + f] * ws[OFF_T0 + f] + Wn[f * 128 + t] * ws[OFF_V0 + f];
            c1 += Wg[f * 128 + t] * ws[OFF_W1 + f];
        }
        ws[OFF_A0 + t] = a0;
        ws[OFF_B0 + t] = b0;
        ws[OFF_C1 + t] = c1;
    }
}

// ---------- prep 4 (round-2 verified): pack fp16 MFMA fragments, f(g,e)=8g+e ----------
// fragB[ct<8][ks<4][lane][e] = Bmat[32ks+8(l>>4)+e][16ct+(l&15)]
// fragS[ct<24][ks<4][lane][e] = Scat[32ks+8(l>>4)+e][16ct+(l&15)],
//   Scat[k][j] = S1T[k][j] (j<128) | S2T[k][j-128] | C2T[k][j-256]
__global__ void k_prep4(float* __restrict__ ws) {
    h16* fB = (h16*)(ws + OFF_FRAGB);
    h16* fS = (h16*)(ws + OFF_FRAGS);
    const int idx = blockIdx.x * 256 + threadIdx.x;     // grid covers 65536
    if (idx < 16384) {
        const int e = idx & 7, l = (idx >> 3) & 63, ks = (idx >> 9) & 3, ct = idx >> 11;
        const int k = 32 * ks + 8 * (l >> 4) + e, j = 16 * ct + (l & 15);
        fB[idx] = (h16)ws[OFF_BMAT + k * 128 + j];
    } else {
        const int sidx = idx - 16384;
        const int e = sidx & 7, l = (sidx >> 3) & 63, ks = (sidx >> 9) & 3, ct = sidx >> 11;
        const int k = 32 * ks + 8 * (l >> 4) + e, j = 16 * ct + (l & 15);
        float v;
        if (j < 128)      v = ws[OFF_S1T + k * 128 + j];
        else if (j < 256) v = ws[OFF_S2T + k * 128 + (j - 128)];
        else              v = ws[OFF_C2T + k * 128 + (j - 256)];
        fS[sidx] = (h16)v;
    }
}

// ---------- fused main: one wave per batch, zero barriers after prologue ----------
__global__ __launch_bounds__(256, 3) void k_fused(const float* __restrict__ x,
                                                  const float* __restrict__ ws,
                                                  float* __restrict__ out) {
    __shared__ __align__(16) h16 xh[BPB * 2560];     // 20480 B: x fp16, swizzled
    __shared__ __align__(16) h16 fFs[BPB * NN * FW]; // 21120 B: per-wave F buffers
    __shared__ __align__(16) h16 xgl[BPB * 128];     // 1024 B: xg, swizzled
    __shared__ float avbc[BPB][384];                 // 6144 B: avec|bvec|cvec (+bias)
    __shared__ float ab[BPB][40];                    // 640 B: alpha|beta
    __shared__ float cbs[BPB];                       // 16 B
    // total ~48.3 KB -> 3 blocks/CU

    const int t = threadIdx.x, l = t & 63, w = t >> 6;
    const int lc = l & 15, lg = l >> 4;
    const int h = l >> 5, c32 = l & 31;
    const int b0 = blockIdx.x * BPB;
    const half8 h8z = {};

    // ---- pass A: stage x (batch = wave) -> xh fp16 + fused col-max -> xgl ----
    {
        const float4* xp = (const float4*)(x + (size_t)(b0 + w) * 2560) + c32;
        float4 mx = {-INFINITY, -INFINITY, -INFINITY, -INFINITY};
        #pragma unroll
        for (int i = 0; i < 10; ++i) {
            const int row = 2 * i + h;                 // h=0: even rows, h=1: odd
            const float4 v = xp[row * 32];
            const half4v hv = { (h16)v.x, (h16)v.y, (h16)v.z, (h16)v.w };
            *(half4v*)(xh + w * 2560 + swz(row, 4 * c32)) = hv;
            mx.x = fmaxf(mx.x, v.x); mx.y = fmaxf(mx.y, v.y);
            mx.z = fmaxf(mx.z, v.z); mx.w = fmaxf(mx.w, v.w);
        }
        mx.x = fmaxf(mx.x, __shfl_xor(mx.x, 32));
        mx.y = fmaxf(mx.y, __shfl_xor(mx.y, 32));
        mx.z = fmaxf(mx.z, __shfl_xor(mx.z, 32));
        mx.w = fmaxf(mx.w, __shfl_xor(mx.w, 32));
        if (h == 0) {
            const half4v hg = { (h16)mx.x, (h16)mx.y, (h16)mx.z, (h16)mx.w };
            *(half4v*)(xgl + swz(w, 4 * c32)) = hg;
        }
    }
    __syncthreads();

    // ---- matvec (round-2 verified): avbc[b] = bias + Scat^T xg(b) ----
    {
        const half8* fS = (const half8*)(ws + OFF_FRAGS);
        f32x4 sacc[6];
        #pragma unroll
        for (int i = 0; i < 6; ++i) sacc[i] = (f32x4){0.f, 0.f, 0.f, 0.f};
        #pragma unroll
        for (int ks = 0; ks < 4; ++ks) {
            half8 ag = *(const half8*)(xgl + swz(lc < BPB ? lc : 0, 32 * ks + 8 * lg));
            if (lc >= BPB) ag = h8z;
            #pragma unroll
            for (int i = 0; i < 6; ++i) {
                const int ct = 6 * w + i;
                sacc[i] = MFMA16(ag, fS[(ct * 4 + ks) * 64 + l], sacc[i]);
            }
        }
        if (lg == 0) {                               // C/D rows 0..3 = batches 0..3
            #pragma unroll
            for (int i = 0; i < 6; ++i) {
                const int ct = 6 * w + i;
                const int v = ct >> 3, c128 = 16 * (ct & 7) + lc;
                const float bias = (v == 0) ? ws[OFF_A0 + c128]
                                 : (v == 1) ? ws[OFF_B0 + c128] : ws[OFF_C1 + c128];
                #pragma unroll
                for (int r = 0; r < 4; ++r)
                    avbc[r][v * 128 + c128] = sacc[i][r] + bias;
            }
        }
    }
    __syncthreads();

    // ---- alpha/beta dots (round-2 pattern) + c scalar ----
    if (t < BPB * 40) {
        const int bb = t / 40, i = t % 40;
        const int row = (i < 20) ? i : (i - 20);
        const float* av = avbc[bb] + ((i < 20) ? 0 : 128);
        float s = 0.f;
        #pragma unroll
        for (int c8 = 0; c8 < 16; ++c8) {
            const half8 xv = *(const half8*)(xh + bb * 2560 + swz(row, 8 * c8));
            #pragma unroll
            for (int e = 0; e < 8; ++e) s += (float)xv[e] * av[8 * c8 + e];
        }
        ab[bb][i] = s;
    }
    {   // cbs[w] = cbase + xg . cvec   (wave-local, 2 cols/lane)
        const int j0 = l * 2;
        float s = (float)xgl[swz(w, j0)]     * avbc[w][256 + j0]
                + (float)xgl[swz(w, j0 + 1)] * avbc[w][256 + j0 + 1];
        #pragma unroll
        for (int off = 32; off > 0; off >>= 1) s += __shfl_xor(s, off);
        if (l == 0) cbs[w] = s + ws[OFF_CBASE];
    }
    __syncthreads();
    // ================= fully independent per-wave from here =================

    const h16* xhw = xh + w * 2560;
    h16* fFw = fFs + w * NN * FW;

    // hoisted x fragments: serve as F-phase A-op AND M-phase B-op (k_A==k_B
    // for 16x16x32 verified by round 2's pass)
    half8 xa[2][4];
    #pragma unroll
    for (int ks = 0; ks < 4; ++ks) {
        xa[0][ks] = *(const half8*)(xhw + swz(lc, 32 * ks + 8 * lg));
        const int r1 = 16 + lc;
        half8 v = *(const half8*)(xhw + swz(r1 < NN ? r1 : 0, 32 * ks + 8 * lg));
        if (r1 >= NN) v = h8z;
        xa[1][ks] = v;
    }

    // ---- F phase: F = x * B, staged to private LDS (rows 0..19) ----
    {
        const half8* fB = (const half8*)(ws + OFF_FRAGB);
        #pragma unroll
        for (int ct = 0; ct < 8; ++ct) {
            f32x4 f0 = {0.f, 0.f, 0.f, 0.f}, f1 = {0.f, 0.f, 0.f, 0.f};
            #pragma unroll
            for (int ks = 0; ks < 4; ++ks) {
                const half8 bb = fB[(ct * 4 + ks) * 64 + l];
                f0 = MFMA16(xa[0][ks], bb, f0);
                f1 = MFMA16(xa[1][ks], bb, f1);
            }
            #pragma unroll
            for (int r = 0; r < 4; ++r) {
                fFw[(4 * lg + r) * FW + 16 * ct + lc] = (h16)f0[r];
                if (lg == 0) fFw[(16 + r) * FW + 16 * ct + lc] = (h16)f1[r];
            }
        }
    }
    asm volatile("s_waitcnt lgkmcnt(0)" ::: "memory");   // private RAW fence

    // ---- M phase: M[n][m] = sum_j F[n][j] x[m][j] ----
    f32x4 mAcc[2][2];
    #pragma unroll
    for (int nt = 0; nt < 2; ++nt)
        #pragma unroll
        for (int mt = 0; mt < 2; ++mt) mAcc[nt][mt] = (f32x4){0.f, 0.f, 0.f, 0.f};
    #pragma unroll
    for (int nt = 0; nt < 2; ++nt) {
        #pragma unroll
        for (int ks = 0; ks < 4; ++ks) {
            const int row = 16 * nt + lc;
            const half8 aF = *(const half8*)(fFw + (row < NN ? row : 0) * FW + 32 * ks + 8 * lg);
            mAcc[nt][0] = MFMA16(aF, xa[0][ks], mAcc[nt][0]);
            mAcc[nt][1] = MFMA16(aF, xa[1][ks], mAcc[nt][1]);
        }
    }

    // ---- epilogue: + alpha/beta/c, 10*tanh, flattened softmax ----
    // fixed shift: e = exp(z-10) = exp(-20/(exp(2Mv)+1)), exact rescale.
    const float cb = cbs[w];
    const float bm0 = ab[w][20 + lc];
    const float bm1 = (lc < 4) ? ab[w][36 + lc] : 0.f;
    float pv[2][2][4];
    float psum = 0.f;
    #pragma unroll
    for (int nt = 0; nt < 2; ++nt) {
        #pragma unroll
        for (int r = 0; r < 4; ++r) {
            const int n = 16 * nt + 4 * lg + r;
            const float an = (n < NN) ? ab[w][n] : 0.f;
            #pragma unroll
            for (int mt = 0; mt < 2; ++mt) {
                const int m = 16 * mt + lc;
                const bool valid = (n < NN) && (m < NN) && (n != m);
                const float Mv = (mAcc[nt][mt][r] + an + (mt ? bm1 : bm0) + cb) * INVS;
                const float E = __expf(2.f * Mv);
                const float e = valid ? __expf(-20.f / (E + 1.f)) : 0.f;
                pv[nt][mt][r] = e;
                psum += e;
            }
        }
    }
    #pragma unroll
    for (int off = 32; off > 0; off >>= 1) psum += __shfl_xor(psum, off);
    const float inv = 1.f / psum;

    float* ob = out + (size_t)(b0 + w) * 400;
    #pragma unroll
    for (int nt = 0; nt < 2; ++nt) {
        #pragma unroll
        for (int r = 0; r < 4; ++r) {
            const int n = 16 * nt + 4 * lg + r;
            if (n < NN) {
                ob[n * 20 + lc] = pv[nt][0][r] * inv;                 // m = lc < 16
                if (lc < 4) ob[n * 20 + 16 + lc] = pv[nt][1][r] * inv; // m = 16..19
            }
        }
    }
}

extern "C" void kernel_launch(void* const* d_in, const int* in_sizes, int n_in,
                              void* d_out, int out_size, void* d_ws, size_t ws_size,
                              hipStream_t stream) {
    const float* x  = (const float*)d_in[0];
    const float* Wg = (const float*)d_in[1];
    const float* bg = (const float*)d_in[2];
    const float* Wn = (const float*)d_in[3];
    const float* bn = (const float*)d_in[4];
    const float* Wk = (const float*)d_in[5];
    const float* bk = (const float*)d_in[6];
    const float* Wq = (const float*)d_in[7];
    const float* bq = (const float*)d_in[8];
    float* out = (float*)d_out;
    float* ws  = (float*)d_ws;

    k_prep1<<<129, 128, 0, stream>>>(Wk, Wq, bk, bq, bn, bg, ws);
    k_prep2<<<129, 128, 0, stream>>>(Wn, Wg, ws);
    k_prep3<<<129, 128, 0, stream>>>(Wn, Wg, ws);
    k_prep4<<<256, 256, 0, stream>>>(ws);
    k_fused<<<NB / BPB, 256, 0, stream>>>(x, ws, out);
}

// Round 6
// 123.747 us; speedup vs baseline: 3.2820x; 1.0210x over previous
//
#include <hip/hip_runtime.h>
#include <hip/hip_bf16.h>
#include <math.h>

// DecoderActor: B=16384, N=20, DM=128.
// M*sqrt(dm) = x B x^T + alpha_n + beta_m + c, B = Wn^T(Wk^T Wq)Wn,
// alpha/beta/c derived from xg = max_n x[n,:].
// Round 6: two-kernel split.
//   k_abc : per 16 batches, stream x -> xg (HBM-bound), one 16-row MFMA tile
//           -> avec/bvec (h16, bias folded) + scalar c (incl. cbase).
//   k_main: one wave per batch, ZERO barriers. x -> register fragments from
//           global; F_ext = x * [B | avec | bvec] folds alpha/beta into the
//           GEMM; F staged via wave-private LDS (r5-proven); M + softmax.
#define DM 128
#define NN 20
#define NB 16384
#define BPB 4

#define OFF_A      0
#define OFF_AT     16384
#define OFF_WA     32768
#define OFF_WAT    49152
#define OFF_AG     65536
#define OFF_BMAT   81920
#define OFF_S1T    98304
#define OFF_S2T    114688
#define OFF_C2T    131072
#define OFF_U0     147456
#define OFF_V0     147584
#define OFF_T0     147712
#define OFF_W1     147840
#define OFF_AT0    147968
#define OFF_A0     148096
#define OFF_B0     148224
#define OFF_C1     148352
#define OFF_C00    148480
#define OFF_CBASE  148481
// fp16 fragment arrays (packed by k_prep4, round-2/5 verified layout)
#define OFF_FRAGB  149504            // 16384 h16 : Bmat frags (16x16x32 B-op, 8 ct)
#define OFF_FRAGS  (149504 + 8192)   // 49152 h16 : matvec S frags (16x16x32 B-op, 24 ct)
// per-batch vectors from k_abc
#define OFF_AVH    182272            // h16[16384][3][128]... only [0..1] used: avec|bvec
#define OFF_CW     3328000           // f32[16384] : c scalar (incl cbase)
// ws end ~13.4 MB (< r1-proven 17.4 MB)

#define INVS 0.08838834764831845f    // 1/sqrt(128)
#define FW 132                       // fFs row stride in h16

typedef _Float16 h16;
typedef h16 half8 __attribute__((ext_vector_type(8)));
typedef h16 half4v __attribute__((ext_vector_type(4)));
typedef float f32x4 __attribute__((ext_vector_type(4)));

#define MFMA16(a, b, c) __builtin_amdgcn_mfma_f32_16x16x32_f16((a), (b), (c), 0, 0, 0)

// round-2/5 verified XOR swizzle (h16 units)
__device__ __forceinline__ int swz(int row, int col) {
    return (row * 128 + col) ^ ((row & 7) << 3);
}

// ---------- prep 1: A = Wk^T Wq (and A^T), u0, v0, t0, c00 ----------
__global__ void k_prep1(const float* __restrict__ Wk, const float* __restrict__ Wq,
                        const float* __restrict__ bk, const float* __restrict__ bq,
                        const float* __restrict__ bn, const float* __restrict__ bg,
                        float* __restrict__ ws) {
    const int bx = blockIdx.x, t = threadIdx.x;
    __shared__ float sbuf[128];
    if (bx < 128) {
        sbuf[t] = Wk[t * 128 + bx];
        __syncthreads();
        float a = 0.f;
        #pragma unroll 8
        for (int d = 0; d < 128; ++d) a += sbuf[d] * Wq[d * 128 + t];
        ws[OFF_A  + bx * 128 + t] = a;
        ws[OFF_AT + t * 128 + bx] = a;
    } else {
        float u = 0.f, v = 0.f;
        #pragma unroll 8
        for (int d = 0; d < 128; ++d) {
            u += Wk[d * 128 + t] * bq[d];
            v += Wq[d * 128 + t] * bk[d];
        }
        ws[OFF_U0 + t] = u;
        ws[OFF_V0 + t] = v;
        ws[OFF_T0 + t] = bn[t] + bg[t];
        sbuf[t] = bk[t] * bq[t];
        __syncthreads();
        for (int s = 64; s > 0; s >>= 1) { if (t < s) sbuf[t] += sbuf[t + s]; __syncthreads(); }
        if (t == 0) ws[OFF_C00] = sbuf[0];
    }
}

// ---------- prep 2: WA = Wn^T A, WAT = Wn^T A^T, AG = A Wg; w1, At0, c_base ----------
__global__ void k_prep2(const float* __restrict__ Wn, const float* __restrict__ Wg,
                        float* __restrict__ ws) {
    const int bx = blockIdx.x, t = threadIdx.x;
    __shared__ float s1[128], s2[128];
    if (bx < 128) {
        const int r = bx;
        s1[t] = Wn[t * 128 + r];
        s2[t] = ws[OFF_A + r * 128 + t];
        __syncthreads();
        float wa = 0.f, wat = 0.f, ag = 0.f;
        #pragma unroll 4
        for (int e = 0; e < 128; ++e) {
            wa  += s1[e] * ws[OFF_A  + e * 128 + t];
            wat += s1[e] * ws[OFF_AT + e * 128 + t];
            ag  += s2[e] * Wg[e * 128 + t];
        }
        ws[OFF_WA  + r * 128 + t] = wa;
        ws[OFF_WAT + r * 128 + t] = wat;
        ws[OFF_AG  + r * 128 + t] = ag;
    } else {
        const float t0t = ws[OFF_T0 + t], u0t = ws[OFF_U0 + t], v0t = ws[OFF_V0 + t];
        float w1 = 0.f, at0 = 0.f;
        #pragma unroll 8
        for (int e = 0; e < 128; ++e) {
            const float t0e = ws[OFF_T0 + e];
            w1  += (ws[OFF_A + t * 128 + e] + ws[OFF_AT + t * 128 + e]) * t0e;
            at0 +=  ws[OFF_A + t * 128 + e] * t0e;
        }
        w1 += u0t + v0t;
        ws[OFF_W1  + t] = w1;
        ws[OFF_AT0 + t] = at0;
        s1[t] = t0t * (at0 + u0t + v0t);
        __syncthreads();
        for (int s = 64; s > 0; s >>= 1) { if (t < s) s1[t] += s1[t + s]; __syncthreads(); }
        if (t == 0) ws[OFF_CBASE] = s1[0] + ws[OFF_C00];
    }
}

// ---------- prep 3: Bmat, S1t, S2t, C2t; a0, b0, c1 ----------
__global__ void k_prep3(const float* __restrict__ Wn, const float* __restrict__ Wg,
                        float* __restrict__ ws) {
    const int bx = blockIdx.x, t = threadIdx.x;
    __shared__ float wa[128], wat[128], wgc[128];
    if (bx < 128) {
        const int r = bx;
        wa[t]  = ws[OFF_WA  + r * 128 + t];
        wat[t] = ws[OFF_WAT + r * 128 + t];
        wgc[t] = Wg[t * 128 + r];
        __syncthreads();
        float bm = 0.f, s1v = 0.f, s2v = 0.f, c2v = 0.f;
        #pragma unroll 4
        for (int f = 0; f < 128; ++f) {
            bm  += wa[f]  * Wn[f * 128 + t];
            s1v += wa[f]  * Wg[f * 128 + t];
            s2v += wat[f] * Wg[f * 128 + t];
            c2v += wgc[f] * ws[OFF_AG + f * 128 + t];
        }
        ws[OFF_BMAT + r * 128 + t] = bm;
        ws[OFF_S1T + t * 128 + r] = s1v;
        ws[OFF_S2T + t * 128 + r] = s2v;
        ws[OFF_C2T + t * 128 + r] = c2v;
    } else {
        float a0 = 0.f, b0 = 0.f, c1 = 0.f;
        #pragma unroll 8
        for (int f = 0; f < 128; ++f) {
            a0 += ws[OFF_WA  + t * 128 + f] * ws[OFF_T0 + f] + Wn[f * 128 + t] * ws[OFF_U0 + f];
            b0 += ws[OFF_WAT + t * 128 + f] * ws[OFF_T0 + f] + Wn[f * 128 + t] * ws[OFF_V0 + f];
            c1 += Wg[f * 128 + t] * ws[OFF_W1 + f];
        }
        ws[OFF_A0 + t] = a0;
        ws[OFF_B0 + t] = b0;
        ws[OFF_C1 + t] = c1;
    }
}

// ---------- prep 4 (verified): pack fp16 MFMA fragments, f(g,e)=8g+e ----------
__global__ void k_prep4(float* __restrict__ ws) {
    h16* fB = (h16*)(ws + OFF_FRAGB);
    h16* fS = (h16*)(ws + OFF_FRAGS);
    const int idx = blockIdx.x * 256 + threadIdx.x;     // grid covers 65536
    if (idx < 16384) {
        const int e = idx & 7, l = (idx >> 3) & 63, ks = (idx >> 9) & 3, ct = idx >> 11;
        const int k = 32 * ks + 8 * (l >> 4) + e, j = 16 * ct + (l & 15);
        fB[idx] = (h16)ws[OFF_BMAT + k * 128 + j];
    } else {
        const int sidx = idx - 16384;
        const int e = sidx & 7, l = (sidx >> 3) & 63, ks = (sidx >> 9) & 3, ct = sidx >> 11;
        const int k = 32 * ks + 8 * (l >> 4) + e, j = 16 * ct + (l & 15);
        float v;
        if (j < 128)      v = ws[OFF_S1T + k * 128 + j];
        else if (j < 256) v = ws[OFF_S2T + k * 128 + (j - 128)];
        else              v = ws[OFF_C2T + k * 128 + (j - 256)];
        fS[sidx] = (h16)v;
    }
}

// ---------- k_abc: 16 batches/block -> avec/bvec (h16) + c scalar ----------
__global__ __launch_bounds__(256) void k_abc(const float* __restrict__ x,
                                             float* __restrict__ ws) {
    __shared__ __align__(16) h16 xgl[16 * 128];   // 4 KB, swizzled
    __shared__ float cpart[16][4];
    const int t = threadIdx.x, l = t & 63, w = t >> 6;
    const int lc = l & 15, lg = l >> 4;
    const int h = l >> 5, c32 = l & 31;
    const int b0 = blockIdx.x * 16;

    // ---- xg = col-max over 20 rows, 4 batches per wave ----
    #pragma unroll
    for (int q = 0; q < 4; ++q) {
        const int bi = 4 * w + q;
        const float4* xp = (const float4*)(x + (size_t)(b0 + bi) * 2560) + c32;
        float4 mx = xp[h * 32];
        #pragma unroll
        for (int i = 1; i < 10; ++i) {
            const float4 v = xp[(2 * i + h) * 32];
            mx.x = fmaxf(mx.x, v.x); mx.y = fmaxf(mx.y, v.y);
            mx.z = fmaxf(mx.z, v.z); mx.w = fmaxf(mx.w, v.w);
        }
        mx.x = fmaxf(mx.x, __shfl_xor(mx.x, 32));
        mx.y = fmaxf(mx.y, __shfl_xor(mx.y, 32));
        mx.z = fmaxf(mx.z, __shfl_xor(mx.z, 32));
        mx.w = fmaxf(mx.w, __shfl_xor(mx.w, 32));
        if (h == 0) {
            const half4v hg = { (h16)mx.x, (h16)mx.y, (h16)mx.z, (h16)mx.w };
            *(half4v*)(xgl + swz(bi, 4 * c32)) = hg;
        }
    }
    __syncthreads();

    // ---- matvec: A-rows = 16 batches' xg; wave w owns ct = w + 4i ----
    const half8* fS = (const half8*)(ws + OFF_FRAGS);
    f32x4 sacc[6];
    #pragma unroll
    for (int i = 0; i < 6; ++i) sacc[i] = (f32x4){0.f, 0.f, 0.f, 0.f};
    #pragma unroll
    for (int ks = 0; ks < 4; ++ks) {
        const half8 ag = *(const half8*)(xgl + swz(lc, 32 * ks + 8 * lg));
        #pragma unroll
        for (int i = 0; i < 6; ++i) {
            const int ct = w + 4 * i;
            sacc[i] = MFMA16(ag, fS[(ct * 4 + ks) * 64 + l], sacc[i]);
        }
    }
    // avec/bvec (ct 0..15): C/D row = batch 4lg+r, col = 16(ct&7)+lc
    h16* avh = (h16*)(ws + OFF_AVH);
    #pragma unroll
    for (int i = 0; i < 4; ++i) {
        const int ct = w + 4 * i;
        const int v = ct >> 3, c128 = 16 * (ct & 7) + lc;
        const float bias = (v == 0) ? ws[OFF_A0 + c128] : ws[OFF_B0 + c128];
        #pragma unroll
        for (int r = 0; r < 4; ++r)
            avh[((size_t)(b0 + 4 * lg + r) * 3 + v) * 128 + c128] = (h16)(sacc[i][r] + bias);
    }
    // c partials (ct 16..23 -> j = 16w+lc, 16w+64+lc)
    float p[4] = {0.f, 0.f, 0.f, 0.f};
    #pragma unroll
    for (int i = 4; i < 6; ++i) {
        const int j = 16 * (w + 4 * i - 16) + lc;
        const float c1j = ws[OFF_C1 + j];
        #pragma unroll
        for (int r = 0; r < 4; ++r) {
            const float xgv = (float)xgl[swz(4 * lg + r, j)];
            p[r] += (sacc[i][r] + c1j) * xgv;
        }
    }
    #pragma unroll
    for (int r = 0; r < 4; ++r) {
        float v = p[r];
        v += __shfl_xor(v, 1); v += __shfl_xor(v, 2);
        v += __shfl_xor(v, 4); v += __shfl_xor(v, 8);
        if (lc == 0) cpart[4 * lg + r][w] = v;
    }
    __syncthreads();
    if (t < 16)
        ws[OFF_CW + b0 + t] = ws[OFF_CBASE]
                            + cpart[t][0] + cpart[t][1] + cpart[t][2] + cpart[t][3];
}

// ---------- k_main: one wave per batch, zero barriers ----------
__global__ __launch_bounds__(256, 4) void k_main(const float* __restrict__ x,
                                                 const float* __restrict__ ws,
                                                 float* __restrict__ out) {
    __shared__ __align__(16) h16 fFs[BPB * NN * FW];   // 21120 B, wave-private slices
    __shared__ float abL[BPB][40];                     // alpha|beta per wave

    const int t = threadIdx.x, l = t & 63, w = t >> 6;
    const int lc = l & 15, lg = l >> 4;
    const int b = blockIdx.x * BPB + w;
    const half8 h8z = {};

    // ---- x fragments straight from global (L3-resident after k_abc) ----
    const float* xb = x + (size_t)b * 2560;
    half8 xa0[4], xa1[4];
    #pragma unroll
    for (int ks = 0; ks < 4; ++ks) {
        const float4 v0 = *(const float4*)(xb + lc * 128 + 32 * ks + 8 * lg);
        const float4 v1 = *(const float4*)(xb + lc * 128 + 32 * ks + 8 * lg + 4);
        xa0[ks] = (half8){ (h16)v0.x, (h16)v0.y, (h16)v0.z, (h16)v0.w,
                           (h16)v1.x, (h16)v1.y, (h16)v1.z, (h16)v1.w };
    }
    #pragma unroll
    for (int ks = 0; ks < 4; ++ks) {
        half8 v = h8z;
        if (lc < 4) {
            const float4 v0 = *(const float4*)(xb + (16 + lc) * 128 + 32 * ks + 8 * lg);
            const float4 v1 = *(const float4*)(xb + (16 + lc) * 128 + 32 * ks + 8 * lg + 4);
            v = (half8){ (h16)v0.x, (h16)v0.y, (h16)v0.z, (h16)v0.w,
                         (h16)v1.x, (h16)v1.y, (h16)v1.z, (h16)v1.w };
        }
        xa1[ks] = v;
    }
    // ct8 B-operand: col0 = avec, col1 = bvec (h16 from k_abc), else 0
    const h16* avh = (const h16*)(ws + OFF_AVH);
    half8 s8[4];
    #pragma unroll
    for (int ks = 0; ks < 4; ++ks) {
        half8 v = h8z;
        if (lc < 2) v = *(const half8*)(avh + ((size_t)b * 3 + lc) * 128 + 32 * ks + 8 * lg);
        s8[ks] = v;
    }

    h16* fFw = fFs + w * NN * FW;
    const half8* fB = (const half8*)(ws + OFF_FRAGB);

    // ---- F phase: F = x * B, staged to wave-private LDS ----
    #pragma unroll
    for (int ct = 0; ct < 8; ++ct) {
        f32x4 f0 = {0.f, 0.f, 0.f, 0.f}, f1 = {0.f, 0.f, 0.f, 0.f};
        #pragma unroll
        for (int ks = 0; ks < 4; ++ks) {
            const half8 bb = fB[(ct * 4 + ks) * 64 + l];
            f0 = MFMA16(xa0[ks], bb, f0);
            f1 = MFMA16(xa1[ks], bb, f1);
        }
        #pragma unroll
        for (int r = 0; r < 4; ++r) {
            fFw[(4 * lg + r) * FW + 16 * ct + lc] = (h16)f0[r];
            if (lg == 0) fFw[(16 + r) * FW + 16 * ct + lc] = (h16)f1[r];
        }
    }
    // ---- ct8: alpha/beta via same GEMM machinery ----
    {
        f32x4 a0c = {0.f, 0.f, 0.f, 0.f}, a1c = {0.f, 0.f, 0.f, 0.f};
        #pragma unroll
        for (int ks = 0; ks < 4; ++ks) {
            a0c = MFMA16(xa0[ks], s8[ks], a0c);
            a1c = MFMA16(xa1[ks], s8[ks], a1c);
        }
        if (lc == 0) {
            #pragma unroll
            for (int r = 0; r < 4; ++r) abL[w][4 * lg + r] = a0c[r];
            if (lg == 0) {
                #pragma unroll
                for (int r = 0; r < 4; ++r) abL[w][16 + r] = a1c[r];
            }
        }
        if (lc == 1) {
            #pragma unroll
            for (int r = 0; r < 4; ++r) abL[w][20 + 4 * lg + r] = a0c[r];
            if (lg == 0) {
                #pragma unroll
                for (int r = 0; r < 4; ++r) abL[w][36 + r] = a1c[r];
            }
        }
    }
    asm volatile("s_waitcnt lgkmcnt(0)" ::: "memory");   // private RAW fence

    // ---- M phase: M[n][m] = sum_j F[n][j] x[m][j] ----
    f32x4 mAcc[2][2];
    #pragma unroll
    for (int nt = 0; nt < 2; ++nt)
        #pragma unroll
        for (int mt = 0; mt < 2; ++mt) mAcc[nt][mt] = (f32x4){0.f, 0.f, 0.f, 0.f};
    #pragma unroll
    for (int nt = 0; nt < 2; ++nt) {
        #pragma unroll
        for (int ks = 0; ks < 4; ++ks) {
            const int row = 16 * nt + lc;
            const half8 aF = *(const half8*)(fFw + (row < NN ? row : 0) * FW + 32 * ks + 8 * lg);
            mAcc[nt][0] = MFMA16(aF, xa0[ks], mAcc[nt][0]);
            mAcc[nt][1] = MFMA16(aF, xa1[ks], mAcc[nt][1]);
        }
    }

    // ---- epilogue: + alpha/beta/c, 10*tanh, flattened softmax ----
    // fixed shift: e = exp(z-10) = exp(-20/(exp(2Mv)+1)); per-batch c shifts
    // all 400 logits equally (cancels in softmax), so its precision is free.
    const float cb = ws[OFF_CW + b];
    const float bm0 = abL[w][20 + lc];
    const float bm1 = (lc < 4) ? abL[w][36 + lc] : 0.f;
    float pv[2][2][4];
    float psum = 0.f;
    #pragma unroll
    for (int nt = 0; nt < 2; ++nt) {
        #pragma unroll
        for (int r = 0; r < 4; ++r) {
            const int n = 16 * nt + 4 * lg + r;
            const float an = (n < NN) ? abL[w][n] : 0.f;
            #pragma unroll
            for (int mt = 0; mt < 2; ++mt) {
                const int m = 16 * mt + lc;
                const bool valid = (n < NN) && (m < NN) && (n != m);
                const float Mv = (mAcc[nt][mt][r] + an + (mt ? bm1 : bm0) + cb) * INVS;
                const float E = __expf(2.f * Mv);
                const float e = valid ? __expf(-20.f / (E + 1.f)) : 0.f;
                pv[nt][mt][r] = e;
                psum += e;
            }
        }
    }
    #pragma unroll
    for (int off = 32; off > 0; off >>= 1) psum += __shfl_xor(psum, off);
    const float inv = 1.f / psum;

    float* ob = out + (size_t)b * 400;
    #pragma unroll
    for (int nt = 0; nt < 2; ++nt) {
        #pragma unroll
        for (int r = 0; r < 4; ++r) {
            const int n = 16 * nt + 4 * lg + r;
            if (n < NN) {
                ob[n * 20 + lc] = pv[nt][0][r] * inv;
                if (lc < 4) ob[n * 20 + 16 + lc] = pv[nt][1][r] * inv;
            }
        }
    }
}

extern "C" void kernel_launch(void* const* d_in, const int* in_sizes, int n_in,
                              void* d_out, int out_size, void* d_ws, size_t ws_size,
                              hipStream_t stream) {
    const float* x  = (const float*)d_in[0];
    const float* Wg = (const float*)d_in[1];
    const float* bg = (const float*)d_in[2];
    const float* Wn = (const float*)d_in[3];
    const float* bn = (const float*)d_in[4];
    const float* Wk = (const float*)d_in[5];
    const float* bk = (const float*)d_in[6];
    const float* Wq = (const float*)d_in[7];
    const float* bq = (const float*)d_in[8];
    float* out = (float*)d_out;
    float* ws  = (float*)d_ws;

    k_prep1<<<129, 128, 0, stream>>>(Wk, Wq, bk, bq, bn, bg, ws);
    k_prep2<<<129, 128, 0, stream>>>(Wn, Wg, ws);
    k_prep3<<<129, 128, 0, stream>>>(Wn, Wg, ws);
    k_prep4<<<256, 256, 0, stream>>>(ws);
    k_abc<<<NB / 16, 256, 0, stream>>>(x, ws);
    k_main<<<NB / BPB, 256, 0, stream>>>(x, ws, out);
}